// Round 3
// baseline (68.415 us; speedup 1.0000x reference)
//
#include <hip/hip_runtime.h>

// Problem constants
#define NH 64
#define NW 64
#define ND 32
#define LTOT (NH * NW * ND)   // 131072
#define NBLK 512              // main-kernel grid

// Symmetric-pair formulation (exact, proven R2-R8):
//   loss * L = sum_{unordered in-bounds pairs, 7x7x3 nbhd} 2*k_pq*(1 - y0p*y0q - y1p*y1q)
//            + sum_p (147 - nh*nw*nd) * k_oob(p)
// C=2 softmax identity: y1 = 1-y0  =>  (1 - y0p y0q - y1p y1q) = fma(y0q, 1-2*y0c, y0c).
// No atomics in the hot path (R7). 512 blocks x 1024 thr, 4 wave-uniform subsets (R8).
// R9: interior-block fast path, fma-accumulate.
// R10/R11: z-neighbor taps via intra-wave shuffle (d maps to lanes) -- global
// loads 40 -> 14/thread. Result: only -0.5us => main kernel is issue/latency
// bound, not VMEM bound; inner loop is done.
// R12 (this round): FUSE the reduce kernel into the main kernel via the
// last-block-done pattern. The 2nd graph node cost ~3-5us of serialized
// critical path (launch gap + 1-wave kernel) just to sum 512 floats.
//   - ticket lives in a __device__ global (module .data, NOT harness-poisoned;
//     winner re-arms it to 0 each iteration, safe since winner is last).
//   - cross-XCD coherence (G12/G16): device-scope atomics on BOTH sides
//     (atomicExch publish / atomicAdd(+0.0f) fetch) -- no reliance on
//     dispatch-boundary cache invalidation semantics.
//   - winner reproduces the old reduce_kernel's exact float grouping and
//     shuffle tree => bitwise-identical output (absmax stays 0.0).

__device__ int g_ticket = 0;

__global__ __launch_bounds__(1024, 8)
void gatedcrf3d_kernel(const float* __restrict__ y,       // (2, L) -- only plane 0 read
                       const float* __restrict__ sample,  // (1, L)
                       const float* __restrict__ spacing, // (3,)
                       float* __restrict__ partial,       // (NBLK,) in ws
                       float* __restrict__ out)           // (1,)
{
    const int tid = threadIdx.x;
    const int sub = tid >> 8;                    // 0..3, uniform per 4-wave group
    const int v   = tid & 255;                   // voxel slot in block (256 voxels)

    const int h  = blockIdx.x >> 3;              // provably scalar
    const int wt = blockIdx.x & 7;               // w-tile, scalar
    const int w  = (wt << 3) + (v >> 5);
    const int d  = v & 31;
    const int p  = (h << 11) + (w << 5) + d;

    constexpr float L2E  = 1.4426950408889634f;  // log2(e)
    constexpr float NHL2 = -0.5f * L2E;

    const float sH = spacing[0] * 0.2f;          // / SIGMA_XY
    const float sW = spacing[1] * 0.2f;
    const float sD = spacing[2] * 0.2f;
    const float nh2 = NHL2 * sH * sH;            // -0.5*log2e pre-folded
    const float nw2 = NHL2 * sW * sW;
    const float nd2 = NHL2 * sD * sD;

    const float sc  = sample[p];                 // raw center sample (kept for shuffle)
    const float ic  = sc * 10.0f;                // / SIGMA_IMG
    const float y0c = y[p];
    const float acv = __builtin_fmaf(-2.0f, y0c, 1.0f);   // 1 - 2*y0c

    const bool vm = d > 0;
    const bool vp = d < ND - 1;

    float acc = 0.0f, extra = 0.0f;

    // Boundary path: full h/w clamps + per-tap validity; z-taps via shuffle.
    auto PB = [&](int dh, int dw) {              // dh,dw literals -> const-folded
        const int hh = h + dh;                   // dh >= 0 always
        const int ww = w + dw;
        const bool ibhw = (hh < NH) & ((unsigned)ww < NW);
        const int hc = min(hh, NH - 1);
        const int wc = min(max(ww, 0), NW - 1);
        const int q1 = (hc << 11) + (wc << 5) + d;
        const float spat0 = nh2 * (float)(dh * dh) + nw2 * (float)(dw * dw);
        const float spat1 = spat0 + nd2;
        const float s1 = sample[q1];
        const float a1 = y[q1];
        const float s0 = __shfl_up(s1, 1, 64);   // = sample[q1-1] where it matters
        const float s2 = __shfl_down(s1, 1, 64); // = sample[q1+1] where it matters
        const float a0 = __shfl_up(a1, 1, 64);
        const float a2 = __shfl_down(a1, 1, 64);

        float di, arg, k, t;
        di  = __builtin_fmaf(s0, 10.0f, -ic);
        arg = __builtin_fmaf(di * NHL2, di, spat1);
        k   = __builtin_exp2f(arg);
        t   = __builtin_fmaf(a0, acv, y0c);
        acc += (ibhw & vm) ? k * t : 0.0f;

        di  = __builtin_fmaf(s1, 10.0f, -ic);
        arg = __builtin_fmaf(di * NHL2, di, spat0);
        k   = __builtin_exp2f(arg);
        t   = __builtin_fmaf(a1, acv, y0c);
        acc += ibhw ? k * t : 0.0f;

        di  = __builtin_fmaf(s2, 10.0f, -ic);
        arg = __builtin_fmaf(di * NHL2, di, spat1);
        k   = __builtin_exp2f(arg);
        t   = __builtin_fmaf(a2, acv, y0c);
        acc += (ibhw & vp) ? k * t : 0.0f;
    };

    // Interior path: no h/w bounds logic; only z-edge selects remain.
    auto PBI = [&](int dh, int dw) {
        const int q1 = ((h + dh) << 11) + ((w + dw) << 5) + d;
        const float spat0 = nh2 * (float)(dh * dh) + nw2 * (float)(dw * dw);
        const float spat1 = spat0 + nd2;
        const float s1 = sample[q1];
        const float a1 = y[q1];
        const float s0 = __shfl_up(s1, 1, 64);
        const float s2 = __shfl_down(s1, 1, 64);
        const float a0 = __shfl_up(a1, 1, 64);
        const float a2 = __shfl_down(a1, 1, 64);

        float di, arg, k, t;
        di  = __builtin_fmaf(s0, 10.0f, -ic);
        arg = __builtin_fmaf(di * NHL2, di, spat1);
        k   = __builtin_exp2f(arg);
        t   = __builtin_fmaf(a0, acv, y0c);
        acc += vm ? k * t : 0.0f;

        di  = __builtin_fmaf(s1, 10.0f, -ic);
        arg = __builtin_fmaf(di * NHL2, di, spat0);
        k   = __builtin_exp2f(arg);
        t   = __builtin_fmaf(a1, acv, y0c);
        acc = __builtin_fmaf(k, t, acc);         // always valid: single fmac

        di  = __builtin_fmaf(s2, 10.0f, -ic);
        arg = __builtin_fmaf(di * NHL2, di, spat1);
        k   = __builtin_exp2f(arg);
        t   = __builtin_fmaf(a2, acv, y0c);
        acc += vp ? k * t : 0.0f;
    };

    const bool interior = (h <= NH - 1 - 3) & (wt >= 1) & (wt <= 6);

    if (interior) {
        switch (sub) {
          case 0: PBI(0,1); PBI(0,2); PBI(0,3); PBI(1,-3); PBI(1,-2); PBI(1,-1); break;
          case 1: PBI(1,0); PBI(1,1); PBI(1,2); PBI(1,3);  PBI(2,-3); PBI(2,-2); break;
          case 2: PBI(2,-1); PBI(2,0); PBI(2,1); PBI(2,2); PBI(2,3);  PBI(3,-3); break;
          case 3: PBI(3,-2); PBI(3,-1); PBI(3,0); PBI(3,1); PBI(3,2); PBI(3,3);  break;
        }
    } else {
        switch (sub) {
          case 0: PB(0,1); PB(0,2); PB(0,3); PB(1,-3); PB(1,-2); PB(1,-1); break;
          case 1: PB(1,0); PB(1,1); PB(1,2); PB(1,3);  PB(2,-3); PB(2,-2); break;
          case 2: PB(2,-1); PB(2,0); PB(2,1); PB(2,2); PB(2,3);  PB(3,-3); break;
          case 3: PB(3,-2); PB(3,-1); PB(3,0); PB(3,1); PB(3,2); PB(3,3);  break;
        }
    }

    if (sub == 0) {
        // lone (0,0,1) half-offset: center values of lane d+1, no loads needed
        const float sq = __shfl_down(sc, 1, 64);   // sample[p+1] where vp
        const float aq = __shfl_down(y0c, 1, 64);  // y[p+1] where vp
        const float di  = __builtin_fmaf(sq, 10.0f, -ic);
        const float arg = __builtin_fmaf(di * NHL2, di, nd2);
        const float k   = __builtin_exp2f(arg);
        const float t   = __builtin_fmaf(aq, acv, y0c);
        acc += vp ? k * t : 0.0f;
    } else if (sub == 3) {
        // out-of-bounds taps, closed form (zero-padded unfold semantics)
        const int nhv = min(h, 3) + min(NH - 1 - h, 3) + 1;
        const int nwv = min(w, 3) + min(NW - 1 - w, 3) + 1;
        const int ndv = min(d, 1) + min(ND - 1 - d, 1) + 1;
        const int cnt = 147 - nhv * nwv * ndv;
        const float argo = nh2 * (float)(h * h) + nw2 * (float)(w * w)
                         + nd2 * (float)(d * d) + NHL2 * ic * ic;
        extra = (float)cnt * __builtin_exp2f(argo);
    }

    float contrib = __builtin_fmaf(2.0f, acc, extra);

    // wave64 reduction -> LDS -> per-block partial
    #pragma unroll
    for (int off = 32; off > 0; off >>= 1)
        contrib += __shfl_down(contrib, off, 64);

    __shared__ float red[16];
    __shared__ int winner;
    if ((tid & 63) == 0) red[tid >> 6] = contrib;
    __syncthreads();
    if (tid == 0) {
        float s = 0.0f;
        #pragma unroll
        for (int i = 0; i < 16; ++i) s += red[i];
        // device-coherent publish (performed at the coherence point)
        atomicExch(&partial[blockIdx.x], s);
        __threadfence();                         // order publish before ticket
        const int t = atomicAdd(&g_ticket, 1);
        winner = (t == NBLK - 1) ? 1 : 0;
    }
    __syncthreads();

    if (winner && tid < 64) {
        __threadfence();                         // acquire side
        // Reproduce old reduce_kernel bitwise: a=partial4[tid], b=partial4[tid+64]
        float pa[4], pb[4];
        #pragma unroll
        for (int j = 0; j < 4; ++j)
            pa[j] = atomicAdd(&partial[4 * tid + j], 0.0f);        // coherent fetch
        #pragma unroll
        for (int j = 0; j < 4; ++j)
            pb[j] = atomicAdd(&partial[256 + 4 * tid + j], 0.0f);  // coherent fetch
        float s = ((pa[0] + pa[1]) + (pa[2] + pa[3]))
                + ((pb[0] + pb[1]) + (pb[2] + pb[3]));

        #pragma unroll
        for (int off = 32; off > 0; off >>= 1)
            s += __shfl_down(s, off, 64);

        if (tid == 0) {
            out[0] = s * (1.0f / (float)LTOT);
            atomicExch(&g_ticket, 0);            // re-arm for next graph replay
        }
    }
}

extern "C" void kernel_launch(void* const* d_in, const int* in_sizes, int n_in,
                              void* d_out, int out_size, void* d_ws, size_t ws_size,
                              hipStream_t stream) {
    const float* y       = (const float*)d_in[0]; // y_hat_softmax (1,2,64,64,32)
    const float* sample  = (const float*)d_in[1]; // (1,1,64,64,32)
    const float* spacing = (const float*)d_in[2]; // (3,1)
    float* out     = (float*)d_out;
    float* partial = (float*)d_ws;                // NBLK floats

    gatedcrf3d_kernel<<<NBLK, 1024, 0, stream>>>(y, sample, spacing, partial, out);
}

// Round 4
// 63.591 us; speedup vs baseline: 1.0759x; 1.0759x over previous
//
#include <hip/hip_runtime.h>

// Problem constants
#define NH 64
#define NW 64
#define ND 32
#define LTOT (NH * NW * ND)   // 131072
#define NBLK 512              // main-kernel grid

// Symmetric-pair formulation (exact, proven R2-R8):
//   loss * L = sum_{unordered in-bounds pairs, 7x7x3 nbhd} 2*k_pq*(1 - y0p*y0q - y1p*y1q)
//            + sum_p (147 - nh*nw*nd) * k_oob(p)
// C=2 softmax identity: y1 = 1-y0  =>  (1 - y0p y0q - y1p y1q) = fma(y0q, 1-2*y0c, y0c).
// No atomics (R7). 512 blocks x 1024 thr, 4 wave-uniform subsets x 6 pairs (R8).
// R9: interior-block fast path, fma-accumulate, single-wave reduce kernel.
// R10/R11: z-neighbors via shuffle -> only -0.8% => NOT VMEM-bound.
// R12: last-block-done fusion REGRESSED +4.5us (cross-XCD fence/atomic tail
//      costs more than a 1-wave reduce dispatch). Reverted to two kernels.
// R13 (this round): kill DS-pipe contention. R10 used 4 ds_bpermute PER PAIR
// (26/thread; ~830 wave-DS-ops/CU across 32 waves -> per-CU LDS-pipe serialization).
// Re-partition the pair set: lane d now computes the z+-1 taps whose CENTER is
// p-+z^, using its OWN loaded (s1,a1) and the neighbor's center scalars
// (ic,y0c) -- shuffled ONCE per thread (4 DS ops total, acv via fma).
// Bijective re-assignment of the identical pair multiset; every k*t product is
// bit-identical, only the accumulation lane changes (reduction-order bits only).

__global__ __launch_bounds__(1024, 8)
void gatedcrf3d_kernel(const float* __restrict__ y,       // (2, L) -- only plane 0 read
                       const float* __restrict__ sample,  // (1, L)
                       const float* __restrict__ spacing, // (3,)
                       float* __restrict__ partial)       // (NBLK,)
{
    const int tid = threadIdx.x;
    const int sub = tid >> 8;                    // 0..3, uniform per 4-wave group
    const int v   = tid & 255;                   // voxel slot in block (256 voxels)

    const int h  = blockIdx.x >> 3;              // provably scalar
    const int wt = blockIdx.x & 7;               // w-tile, scalar
    const int w  = (wt << 3) + (v >> 5);
    const int d  = v & 31;
    const int p  = (h << 11) + (w << 5) + d;

    constexpr float L2E  = 1.4426950408889634f;  // log2(e)
    constexpr float NHL2 = -0.5f * L2E;

    const float sH = spacing[0] * 0.2f;          // / SIGMA_XY
    const float sW = spacing[1] * 0.2f;
    const float sD = spacing[2] * 0.2f;
    const float nh2 = NHL2 * sH * sH;            // -0.5*log2e pre-folded
    const float nw2 = NHL2 * sW * sW;
    const float nd2 = NHL2 * sD * sD;

    const float sc  = sample[p];                 // raw center sample
    const float ic  = sc * 10.0f;                // / SIGMA_IMG
    const float y0c = y[p];
    const float acv = __builtin_fmaf(-2.0f, y0c, 1.0f);   // 1 - 2*y0c

    // Neighbor-center scalars: 4 DS ops TOTAL per thread (was 4 per pair).
    // Seam/edge lanes get garbage here -- consumed only under vm/vp masks.
    const float icu = __shfl_up(ic, 1, 64);      // center values of p - z^
    const float y0u = __shfl_up(y0c, 1, 64);
    const float icd = __shfl_down(ic, 1, 64);    // center values of p + z^
    const float y0d = __shfl_down(y0c, 1, 64);
    const float acvu = __builtin_fmaf(-2.0f, y0u, 1.0f);  // bit-identical to lane d-1's acv
    const float acvd = __builtin_fmaf(-2.0f, y0d, 1.0f);

    const bool vm = d > 0;
    const bool vp = d < ND - 1;

    float acc = 0.0f, extra = 0.0f;

    // Boundary path: full h/w clamps + per-tap validity.
    // Three taps per pair-offset, all using this lane's loaded (s1,a1):
    //   z0 : pair (p, q)          center = self        mask ibhw
    //   zm : pair (p - z^, q)     center = shuffled-up mask ibhw & vm
    //   zp : pair (p + z^, q)     center = shuffled-dn mask ibhw & vp
    auto PB = [&](int dh, int dw) {              // dh,dw literals -> const-folded
        const int hh = h + dh;                   // dh >= 0 always
        const int ww = w + dw;
        const bool ibhw = (hh < NH) & ((unsigned)ww < NW);
        const int hc = min(hh, NH - 1);
        const int wc = min(max(ww, 0), NW - 1);
        const int q1 = (hc << 11) + (wc << 5) + d;
        const float spat0 = nh2 * (float)(dh * dh) + nw2 * (float)(dw * dw);
        const float spat1 = spat0 + nd2;
        const float s1 = sample[q1];
        const float a1 = y[q1];

        float di, arg, k, t;
        di  = __builtin_fmaf(s1, 10.0f, -ic);
        arg = __builtin_fmaf(di * NHL2, di, spat0);
        k   = __builtin_exp2f(arg);
        t   = __builtin_fmaf(a1, acv, y0c);
        acc += ibhw ? k * t : 0.0f;

        di  = __builtin_fmaf(s1, 10.0f, -icu);
        arg = __builtin_fmaf(di * NHL2, di, spat1);
        k   = __builtin_exp2f(arg);
        t   = __builtin_fmaf(a1, acvu, y0u);
        acc += (ibhw & vm) ? k * t : 0.0f;

        di  = __builtin_fmaf(s1, 10.0f, -icd);
        arg = __builtin_fmaf(di * NHL2, di, spat1);
        k   = __builtin_exp2f(arg);
        t   = __builtin_fmaf(a1, acvd, y0d);
        acc += (ibhw & vp) ? k * t : 0.0f;
    };

    // Interior path: no h/w bounds logic; only z-edge selects remain.
    auto PBI = [&](int dh, int dw) {
        const int q1 = ((h + dh) << 11) + ((w + dw) << 5) + d;
        const float spat0 = nh2 * (float)(dh * dh) + nw2 * (float)(dw * dw);
        const float spat1 = spat0 + nd2;
        const float s1 = sample[q1];
        const float a1 = y[q1];

        float di, arg, k, t;
        di  = __builtin_fmaf(s1, 10.0f, -ic);
        arg = __builtin_fmaf(di * NHL2, di, spat0);
        k   = __builtin_exp2f(arg);
        t   = __builtin_fmaf(a1, acv, y0c);
        acc = __builtin_fmaf(k, t, acc);         // always valid: single fmac

        di  = __builtin_fmaf(s1, 10.0f, -icu);
        arg = __builtin_fmaf(di * NHL2, di, spat1);
        k   = __builtin_exp2f(arg);
        t   = __builtin_fmaf(a1, acvu, y0u);
        acc += vm ? k * t : 0.0f;

        di  = __builtin_fmaf(s1, 10.0f, -icd);
        arg = __builtin_fmaf(di * NHL2, di, spat1);
        k   = __builtin_exp2f(arg);
        t   = __builtin_fmaf(a1, acvd, y0d);
        acc += vp ? k * t : 0.0f;
    };

    const bool interior = (h <= NH - 1 - 3) & (wt >= 1) & (wt <= 6);

    if (interior) {
        switch (sub) {
          case 0: PBI(0,1); PBI(0,2); PBI(0,3); PBI(1,-3); PBI(1,-2); PBI(1,-1); break;
          case 1: PBI(1,0); PBI(1,1); PBI(1,2); PBI(1,3);  PBI(2,-3); PBI(2,-2); break;
          case 2: PBI(2,-1); PBI(2,0); PBI(2,1); PBI(2,2); PBI(2,3);  PBI(3,-3); break;
          case 3: PBI(3,-2); PBI(3,-1); PBI(3,0); PBI(3,1); PBI(3,2); PBI(3,3);  break;
        }
    } else {
        switch (sub) {
          case 0: PB(0,1); PB(0,2); PB(0,3); PB(1,-3); PB(1,-2); PB(1,-1); break;
          case 1: PB(1,0); PB(1,1); PB(1,2); PB(1,3);  PB(2,-3); PB(2,-2); break;
          case 2: PB(2,-1); PB(2,0); PB(2,1); PB(2,2); PB(2,3);  PB(3,-3); break;
          case 3: PB(3,-2); PB(3,-1); PB(3,0); PB(3,1); PB(3,2); PB(3,3);  break;
        }
    }

    if (sub == 0) {
        // lone (0,0,1)-offset pair, re-partitioned: lane d computes pair
        // (p - z^, p) from its OWN center values + shuffled-up neighbor center.
        // Bit-identical to the old lane d-1 computation of pair (p', p'+z^).
        const float di  = __builtin_fmaf(sc, 10.0f, -icu);
        const float arg = __builtin_fmaf(di * NHL2, di, nd2);
        const float k   = __builtin_exp2f(arg);
        const float t   = __builtin_fmaf(y0c, acvu, y0u);
        acc += vm ? k * t : 0.0f;
    } else if (sub == 3) {
        // out-of-bounds taps, closed form (zero-padded unfold semantics)
        const int nhv = min(h, 3) + min(NH - 1 - h, 3) + 1;
        const int nwv = min(w, 3) + min(NW - 1 - w, 3) + 1;
        const int ndv = min(d, 1) + min(ND - 1 - d, 1) + 1;
        const int cnt = 147 - nhv * nwv * ndv;
        const float argo = nh2 * (float)(h * h) + nw2 * (float)(w * w)
                         + nd2 * (float)(d * d) + NHL2 * ic * ic;
        extra = (float)cnt * __builtin_exp2f(argo);
    }

    float contrib = __builtin_fmaf(2.0f, acc, extra);

    // wave64 reduction -> LDS -> ONE PLAIN STORE per block (no atomics)
    #pragma unroll
    for (int off = 32; off > 0; off >>= 1)
        contrib += __shfl_down(contrib, off, 64);

    __shared__ float red[16];
    if ((tid & 63) == 0) red[tid >> 6] = contrib;
    __syncthreads();
    if (tid == 0) {
        float s = 0.0f;
        #pragma unroll
        for (int i = 0; i < 16; ++i) s += red[i];
        partial[blockIdx.x] = s;
    }
}

// Final reduce: ONE wave, 2 float4 per lane over 512 partials; no LDS, no barrier.
__global__ __launch_bounds__(64)
void reduce_kernel(const float4* __restrict__ partial4, float* __restrict__ out)
{
    const int tid = threadIdx.x;
    const float4 a = partial4[tid];
    const float4 b = partial4[tid + 64];
    float s = ((a.x + a.y) + (a.z + a.w)) + ((b.x + b.y) + (b.z + b.w));

    #pragma unroll
    for (int off = 32; off > 0; off >>= 1)
        s += __shfl_down(s, off, 64);

    if (tid == 0)
        out[0] = s * (1.0f / (float)LTOT);
}

extern "C" void kernel_launch(void* const* d_in, const int* in_sizes, int n_in,
                              void* d_out, int out_size, void* d_ws, size_t ws_size,
                              hipStream_t stream) {
    const float* y       = (const float*)d_in[0]; // y_hat_softmax (1,2,64,64,32)
    const float* sample  = (const float*)d_in[1]; // (1,1,64,64,32)
    const float* spacing = (const float*)d_in[2]; // (3,1)
    float* out     = (float*)d_out;
    float* partial = (float*)d_ws;                // NBLK floats

    gatedcrf3d_kernel<<<NBLK, 1024, 0, stream>>>(y, sample, spacing, partial);
    reduce_kernel<<<1, 64, 0, stream>>>((const float4*)partial, out);
}